// Round 16
// baseline (659.831 us; speedup 1.0000x reference)
//
#include <hip/hip_runtime.h>
#include <hip/hip_bf16.h>

#define N_TOK 8192
#define D_DIM 1024
#define E_NUM 8
#define H_DIM 2730
#define HP    2816     // 22*128 padded h-cols
#define NP    5632     // 2*HP = interleaved B' rows
#define NROWS (N_TOK*2)
#define MAXTILES 136   // sum ceil(ne/128) <= 135
#define MAXT256  72    // sum ceil(ne/256) <= 71

typedef __bf16 bf16;
typedef __bf16 bf16x8 __attribute__((ext_vector_type(8)));
typedef __bf16 bf16x4 __attribute__((ext_vector_type(4)));
typedef float  f32x4  __attribute__((ext_vector_type(4)));

__device__ __forceinline__ void gload_lds16(const bf16* g, bf16* l) {
  __builtin_amdgcn_global_load_lds((const __attribute__((address_space(1))) void*)g,
                                   (__attribute__((address_space(3))) void*)l, 16, 0, 0);
}
#define VMCNT(n) asm volatile("s_waitcnt vmcnt(" #n ")" ::: "memory")
#define LGKM0()  asm volatile("s_waitcnt lgkmcnt(0)" ::: "memory")
#define BAR() __builtin_amdgcn_s_barrier()

// ---------- conv: build interleaved B' [e][5632][1024] bf16 ----------
__global__ void conv13_kernel(const float* __restrict__ w1, const float* __restrict__ w3,
                              bf16* __restrict__ Bp) {
  int i = blockIdx.x * blockDim.x + threadIdx.x;      // (e, r', c8)
  if (i >= E_NUM * NP * 128) return;
  int c8 = i & 127;
  int r  = (i >> 7) % NP;
  int e  = i / (NP * 128);
  int hc = ((r >> 5) << 4) + (r & 15);
  bf16x8 o;
  if (hc < H_DIM) {
    const float* s = (((r >> 4) & 1) ? w3 : w1) + ((long)e * H_DIM + hc) * D_DIM + c8 * 8;
    float4 a0 = ((const float4*)s)[0], a1 = ((const float4*)s)[1];
    o[0]=(bf16)a0.x; o[1]=(bf16)a0.y; o[2]=(bf16)a0.z; o[3]=(bf16)a0.w;
    o[4]=(bf16)a1.x; o[5]=(bf16)a1.y; o[6]=(bf16)a1.z; o[7]=(bf16)a1.w;
  } else {
    #pragma unroll
    for (int j = 0; j < 8; j++) o[j] = (bf16)0.f;
  }
  ((bf16x8*)Bp)[i] = o;
}

__global__ void conv_w2_kernel(const float* __restrict__ src, bf16* __restrict__ dst) {
  int i = blockIdx.x * blockDim.x + threadIdx.x;      // row*(HP/8) + c8
  if (i >= E_NUM * D_DIM * (HP / 8)) return;
  int c8 = i % (HP / 8);
  int row = i / (HP / 8);
  int c = c8 * 8;
  const float* s = src + (long)row * H_DIM + c;
  bf16x8 o;
  #pragma unroll
  for (int j = 0; j < 8; j++) o[j] = (c + j < H_DIM) ? (bf16)s[j] : (bf16)0.f;
  ((bf16x8*)dst)[i] = o;
}

// ---------------- router ----------------
__global__ void router_kernel(const float* __restrict__ x, const float* __restrict__ gw,
                              int* __restrict__ topi, float* __restrict__ topw,
                              int* __restrict__ counts) {
  int t = blockIdx.x * (blockDim.x >> 6) + (threadIdx.x >> 6);
  int lane = threadIdx.x & 63;
  if (t >= N_TOK) return;
  const float* xr = x + (long)t * D_DIM;
  float acc[E_NUM];
  #pragma unroll
  for (int e = 0; e < E_NUM; e++) acc[e] = 0.f;
  for (int j = 0; j < D_DIM / 64; j++) {
    float xv = xr[j * 64 + lane];
    #pragma unroll
    for (int e = 0; e < E_NUM; e++) acc[e] += xv * gw[e * D_DIM + j * 64 + lane];
  }
  #pragma unroll
  for (int e = 0; e < E_NUM; e++) {
    float v = acc[e];
    #pragma unroll
    for (int s = 32; s > 0; s >>= 1) v += __shfl_xor(v, s, 64);
    acc[e] = v;
  }
  if (lane == 0) {
    int b0 = -1, b1 = -1; float v0 = -1e30f, v1 = -1e30f;
    #pragma unroll
    for (int e = 0; e < E_NUM; e++) {
      float v = acc[e];
      if (v > v0) { v1 = v0; b1 = b0; v0 = v; b0 = e; }
      else if (v > v1) { v1 = v; b1 = e; }
    }
    float w0 = 1.f / (1.f + expf(v1 - v0));
    topi[t * 2] = b0; topi[t * 2 + 1] = b1;
    topw[t * 2] = w0; topw[t * 2 + 1] = 1.f - w0;
    atomicAdd(&counts[b0], 1); atomicAdd(&counts[b1], 1);
  }
}

// parallel tile-list build
__global__ void tiles_kernel(const int* __restrict__ counts, int* __restrict__ offs,
                             int* __restrict__ tlist, int* __restrict__ tlist2) {
  __shared__ int so[E_NUM + 1], sb[E_NUM + 1], sb2[E_NUM + 1];
  int t = threadIdx.x;
  if (t == 0) {
    int s = 0, b = 0, b2 = 0;
    for (int e = 0; e < E_NUM; e++) {
      so[e] = s; sb[e] = b; sb2[e] = b2;
      int ne = counts[e];
      s += ne; b += (ne + 127) >> 7; b2 += (ne + 255) >> 8;
    }
    so[E_NUM] = s; sb[E_NUM] = b; sb2[E_NUM] = b2;
  }
  __syncthreads();
  if (t <= E_NUM) offs[t] = so[t];
  for (int i = t; i < MAXTILES; i += blockDim.x) {
    int v = -1;
    #pragma unroll
    for (int e = 0; e < E_NUM; e++)
      if (i >= sb[e] && i < sb[e + 1]) v = (e << 8) | (i - sb[e]);
    tlist[i] = v;
  }
  for (int i = t; i < MAXT256; i += blockDim.x) {
    int v = -1;
    #pragma unroll
    for (int e = 0; e < E_NUM; e++)
      if (i >= sb2[e] && i < sb2[e + 1]) v = (e << 8) | (i - sb2[e]);
    tlist2[i] = v;
  }
}

// LDS-aggregated scatter — 8 global atomics/block
__global__ void scatter_kernel(const int* __restrict__ topi, const float* __restrict__ topw,
                               const int* __restrict__ offs, int* __restrict__ cursor,
                               int* __restrict__ rowmap, float* __restrict__ roww,
                               int* __restrict__ rowoftok) {
  __shared__ int hist[E_NUM], base[E_NUM];
  int i = blockIdx.x * blockDim.x + threadIdx.x;
  if (threadIdx.x < E_NUM) hist[threadIdx.x] = 0;
  __syncthreads();
  int e = 0, lpos = 0;
  bool act = (i < NROWS);
  if (act) { e = topi[i]; lpos = atomicAdd(&hist[e], 1); }
  __syncthreads();
  if (threadIdx.x < E_NUM) base[threadIdx.x] = atomicAdd(&cursor[threadIdx.x], hist[threadIdx.x]);
  __syncthreads();
  if (act) {
    int row = offs[e] + base[e] + lpos;
    rowmap[row] = i >> 1;
    roww[row] = topw[i];
    rowoftok[i] = row;
  }
}

__global__ void gather_kernel(const float* __restrict__ x, const int* __restrict__ rowmap,
                              bf16* __restrict__ Xg) {
  int r = blockIdx.x * (blockDim.x >> 6) + (threadIdx.x >> 6);
  int lane = threadIdx.x & 63;
  if (r >= NROWS) return;
  int t = rowmap[r];
  const float4* src = (const float4*)(x + (long)t * D_DIM);
  bf16x4* dst = (bf16x4*)(Xg + (long)r * D_DIM);
  #pragma unroll
  for (int j = 0; j < 4; j++) {
    float4 v = src[j * 64 + lane];
    bf16x4 o; o[0]=(bf16)v.x; o[1]=(bf16)v.y; o[2]=(bf16)v.z; o[3]=(bf16)v.w;
    dst[j * 64 + lane] = o;
  }
}

// combine (split-K2): out[t] = w0*(y0[r0]+y1[r0]) + w1*(y0[r1]+y1[r1])
__global__ void combine_kernel(const bf16* __restrict__ y0p, const bf16* __restrict__ y1p,
                               const int* __restrict__ rowoftok,
                               const float* __restrict__ topw, float* __restrict__ out) {
  int t = blockIdx.x * (blockDim.x >> 6) + (threadIdx.x >> 6);
  int lane = threadIdx.x & 63;
  if (t >= N_TOK) return;
  int r0 = rowoftok[t * 2], r1 = rowoftok[t * 2 + 1];
  float w0 = topw[t * 2], w1 = topw[t * 2 + 1];
  const bf16x8* a0 = (const bf16x8*)(y0p + (long)r0 * D_DIM);
  const bf16x8* a1 = (const bf16x8*)(y1p + (long)r0 * D_DIM);
  const bf16x8* b0 = (const bf16x8*)(y0p + (long)r1 * D_DIM);
  const bf16x8* b1 = (const bf16x8*)(y1p + (long)r1 * D_DIM);
  float* o = out + (long)t * D_DIM;
  #pragma unroll
  for (int j = 0; j < 2; j++) {
    int idx = j * 64 + lane;
    bf16x8 va0 = a0[idx], va1 = a1[idx], vb0 = b0[idx], vb1 = b1[idx];
    float4 v0, v1;
    v0.x = w0*((float)va0[0]+(float)va1[0]) + w1*((float)vb0[0]+(float)vb1[0]);
    v0.y = w0*((float)va0[1]+(float)va1[1]) + w1*((float)vb0[1]+(float)vb1[1]);
    v0.z = w0*((float)va0[2]+(float)va1[2]) + w1*((float)vb0[2]+(float)vb1[2]);
    v0.w = w0*((float)va0[3]+(float)va1[3]) + w1*((float)vb0[3]+(float)vb1[3]);
    v1.x = w0*((float)va0[4]+(float)va1[4]) + w1*((float)vb0[4]+(float)vb1[4]);
    v1.y = w0*((float)va0[5]+(float)va1[5]) + w1*((float)vb0[5]+(float)vb1[5]);
    v1.z = w0*((float)va0[6]+(float)va1[6]) + w1*((float)vb0[6]+(float)vb1[6]);
    v1.w = w0*((float)va0[7]+(float)va1[7]) + w1*((float)vb0[7]+(float)vb1[7]);
    float4* op = (float4*)(o + idx * 8);
    op[0] = v0; op[1] = v1;
  }
}

// ======== r16: gemm1 = r11 kernel + PAIRED bid map (B-panel fetched once per
// row-tile pair). gemm2 = 128Mx128N x K-half, ring-3 48KB -> 3 blocks/CU
// (768 slots, 2176 units -> makespan 1.5*T_half vs 3*T_half). ========

// ---------------- GEMM1: 256(M) x 128(B'cols), BK=32, 4 waves, 72 KB ----------
#define G1_STAGE(SB, T) do { \
    _Pragma("unroll") for (int L_ = 0; L_ < 4; L_++) \
      gload_lds16(aS[L_] + (T) * 32, smem + (SB) + w * 2048 + L_ * 512); \
    _Pragma("unroll") for (int L_ = 0; L_ < 2; L_++) \
      gload_lds16(bS[L_] + (T) * 32, smem + (SB) + 8192 + w * 1024 + L_ * 512); \
  } while (0)

#define G1_READ0(SB) do { \
    _Pragma("unroll") for (int m_ = 0; m_ < 4; m_++) \
      af[m_] = *(const bf16x8*)&smem[(SB) + (w * 64 + m_ * 16 + fr) * 32 + qp]; \
    _Pragma("unroll") for (int q_ = 0; q_ < 4; q_++) \
      bf0[q_] = *(const bf16x8*)&smem[(SB) + 8192 + (q_ * 16 + fr) * 32 + qp]; \
  } while (0)

#define G1_MFMA0() do { __builtin_amdgcn_s_setprio(1); \
    _Pragma("unroll") for (int m_ = 0; m_ < 4; m_++) \
    _Pragma("unroll") for (int q_ = 0; q_ < 4; q_++) \
      acc[m_][q_] = __builtin_amdgcn_mfma_f32_16x16x32_bf16(af[m_], bf0[q_], acc[m_][q_], 0, 0, 0); \
    __builtin_amdgcn_s_setprio(0); } while (0)

#define G1_READ1(SB) do { \
    _Pragma("unroll") for (int q_ = 0; q_ < 4; q_++) \
      bf1[q_] = *(const bf16x8*)&smem[(SB) + 8192 + ((q_ + 4) * 16 + fr) * 32 + qp]; \
  } while (0)

#define G1_MFMA1() do { __builtin_amdgcn_s_setprio(1); \
    _Pragma("unroll") for (int m_ = 0; m_ < 4; m_++) \
    _Pragma("unroll") for (int q_ = 0; q_ < 4; q_++) \
      acc[m_][q_ + 4] = __builtin_amdgcn_mfma_f32_16x16x32_bf16(af[m_], bf1[q_], acc[m_][q_ + 4], 0, 0, 0); \
    __builtin_amdgcn_s_setprio(0); } while (0)

__global__ __launch_bounds__(256, 2) void gemm1_kernel(
    const bf16* __restrict__ Xg, const bf16* __restrict__ Bp,
    const int* __restrict__ counts, const int* __restrict__ offs,
    const int* __restrict__ tlist2, bf16* __restrict__ h) {
  int bid = blockIdx.x;
  int pair = bid / 88, within = bid - pair * 88;
  int col = within >> 1, tp = within & 1;             // tp innermost: B-panel pairing
  int tile = pair * 2 + tp;
  int te = tlist2[tile];
  if (te < 0) return;
  int e = te >> 8, tm = te & 255;
  int ne = counts[e];
  int row_base = offs[e];
  int n0 = col * 128;                                 // B'-col base

  __shared__ bf16 smem[3 * 12288];                    // 72 KB: [slot][A 8192 | B 4096]
  int tid = threadIdx.x, w = tid >> 6, lane = tid & 63;
  int fr = lane & 15, hi = lane >> 4;
  int qp = (hi ^ ((fr >> 1) & 3)) * 8;
  int srcq = ((lane & 3) ^ ((lane >> 3) & 3)) * 8;
  int srow = lane >> 2;

  f32x4 acc[4][8];
  #pragma unroll
  for (int m = 0; m < 4; m++)
    #pragma unroll
    for (int q = 0; q < 8; q++) acc[m][q] = (f32x4)0.f;

  const bf16* Bpe = Bp + (long)e * NP * D_DIM;
  const bf16* aS[4];
  const bf16* bS[2];
  #pragma unroll
  for (int L = 0; L < 4; L++) {
    int ra = row_base + min(tm * 256 + w * 64 + L * 16 + srow, ne - 1);
    aS[L] = Xg + (long)ra * D_DIM + srcq;
  }
  #pragma unroll
  for (int L = 0; L < 2; L++) {
    int rb = n0 + w * 32 + L * 16 + srow;
    bS[L] = Bpe + (long)rb * D_DIM + srcq;
  }

  bf16x8 af[4], bf0[4], bf1[4];

  G1_STAGE(0, 0); G1_STAGE(12288, 1);
  VMCNT(6); BAR();

  int sbC = 0, sbS = 24576;
  for (int t = 0; t < 30; t++) {                      // tiles 0..29; stage 2..31
    G1_READ0(sbC);
    G1_STAGE(sbS, t + 2);
    BAR();
    G1_MFMA0();
    G1_READ1(sbC);
    G1_MFMA1();
    LGKM0(); VMCNT(6); BAR();
    sbC += 12288; if (sbC > 24576) sbC = 0;
    sbS += 12288; if (sbS > 24576) sbS = 0;
  }
  { G1_READ0(sbC); BAR(); G1_MFMA0(); G1_READ1(sbC); G1_MFMA1(); LGKM0(); VMCNT(0); BAR();
    sbC += 12288; if (sbC > 24576) sbC = 0; }
  { G1_READ0(sbC); G1_MFMA0(); G1_READ1(sbC); G1_MFMA1(); }

  // epilogue: q=2p -> gate, q=2p+1 -> up (B' 16-row interleave); h-col base n0/2
  int crow4 = hi * 4;
  #pragma unroll
  for (int m = 0; m < 4; m++)
    #pragma unroll
    for (int j = 0; j < 4; j++) {
      int rloc = tm * 256 + w * 64 + m * 16 + crow4 + j;
      if (rloc < ne) {
        long hrow = (long)(row_base + rloc) * HP;
        #pragma unroll
        for (int p = 0; p < 4; p++) {
          int col2 = (n0 >> 1) + p * 16 + fr;
          float g = acc[m][2 * p][j], u = acc[m][2 * p + 1][j];
          h[hrow + col2] = (bf16)((g / (1.f + __expf(-g))) * u);
        }
      }
    }
}

// -------- GEMM2: 128(M) x 128(N), K-half split, ring-3 48 KB, 3 blocks/CU -----
#define G2_STAGE(SB, T) do { \
    _Pragma("unroll") for (int L_ = 0; L_ < 2; L_++) \
      gload_lds16(aS[L_] + (T) * 32, smem2 + (SB) + w * 1024 + L_ * 512); \
    _Pragma("unroll") for (int L_ = 0; L_ < 2; L_++) \
      gload_lds16(bS[L_] + (T) * 32, smem2 + (SB) + 4096 + w * 1024 + L_ * 512); \
  } while (0)

#define G2_READ(SB) do { \
    _Pragma("unroll") for (int m_ = 0; m_ < 4; m_++) \
      af[m_] = *(const bf16x8*)&smem2[(SB) + (wr * 64 + m_ * 16 + fr) * 32 + qp]; \
    _Pragma("unroll") for (int n_ = 0; n_ < 4; n_++) \
      bfr[n_] = *(const bf16x8*)&smem2[(SB) + 4096 + (wc * 64 + n_ * 16 + fr) * 32 + qp]; \
  } while (0)

#define G2_MFMA() do { __builtin_amdgcn_s_setprio(1); \
    _Pragma("unroll") for (int m_ = 0; m_ < 4; m_++) \
    _Pragma("unroll") for (int n_ = 0; n_ < 4; n_++) \
      acc[m_][n_] = __builtin_amdgcn_mfma_f32_16x16x32_bf16(af[m_], bfr[n_], acc[m_][n_], 0, 0, 0); \
    __builtin_amdgcn_s_setprio(0); } while (0)

__global__ __launch_bounds__(256, 3) void gemm2_kernel(
    const bf16* __restrict__ h, const bf16* __restrict__ w2b,
    const int* __restrict__ counts, const int* __restrict__ offs,
    const int* __restrict__ tlist, bf16* __restrict__ y0p, bf16* __restrict__ y1p) {
  int bid = blockIdx.x;
  int tile = bid >> 4, col = (bid >> 1) & 7, ks = bid & 1;  // col/ks-fastest
  int te = tlist[tile];
  if (te < 0) return;
  int e = te >> 8, tm = te & 255;
  int ne = counts[e];
  int row_base = offs[e];
  int n0 = col * 128;
  int k0 = ks * 1408;                                 // K-half base (44 tiles x 32)

  __shared__ bf16 smem2[3 * 8192];                    // 48 KB: [slot][A 4096 | B 4096]
  int tid = threadIdx.x, w = tid >> 6, lane = tid & 63;
  int wr = w >> 1, wc = w & 1;
  int fr = lane & 15, hi = lane >> 4;
  int qp = (hi ^ ((fr >> 1) & 3)) * 8;
  int srcq = ((lane & 3) ^ ((lane >> 3) & 3)) * 8;
  int srow = lane >> 2;

  f32x4 acc[4][4];
  #pragma unroll
  for (int m = 0; m < 4; m++)
    #pragma unroll
    for (int n = 0; n < 4; n++) acc[m][n] = (f32x4)0.f;

  const bf16* w2e = w2b + (long)e * D_DIM * HP;
  const bf16* aS[2];
  const bf16* bS[2];
  #pragma unroll
  for (int L = 0; L < 2; L++) {
    int ra = row_base + min(tm * 128 + w * 32 + L * 16 + srow, ne - 1);
    aS[L] = h + (long)ra * HP + k0 + srcq;
    int rb = n0 + w * 32 + L * 16 + srow;
    bS[L] = w2e + (long)rb * HP + k0 + srcq;
  }

  bf16x8 af[4], bfr[4];

  G2_STAGE(0, 0); G2_STAGE(8192, 1);
  VMCNT(4); BAR();

  int sbC = 0, sbS = 16384;
  for (int t = 0; t < 42; t++) {                      // tiles 0..41; stage 2..43
    G2_READ(sbC);
    G2_STAGE(sbS, t + 2);
    BAR();
    G2_MFMA();
    LGKM0(); VMCNT(4); BAR();
    sbC += 8192; if (sbC > 16384) sbC = 0;
    sbS += 8192; if (sbS > 16384) sbS = 0;
  }
  { G2_READ(sbC); BAR(); G2_MFMA(); LGKM0(); VMCNT(0); BAR();
    sbC += 8192; if (sbC > 16384) sbC = 0; }
  { G2_READ(sbC); G2_MFMA(); }

  bf16* y = ks ? y1p : y0p;
  int crow4 = hi * 4;
  #pragma unroll
  for (int m = 0; m < 4; m++)
    #pragma unroll
    for (int j = 0; j < 4; j++) {
      int rloc = tm * 128 + wr * 64 + m * 16 + crow4 + j;
      if (rloc < ne) {
        long yrow = (long)(row_base + rloc) * D_DIM;
        #pragma unroll
        for (int n = 0; n < 4; n++) {
          int col2 = n0 + wc * 64 + n * 16 + fr;
          y[yrow + col2] = (bf16)acc[m][n][j];
        }
      }
    }
}

extern "C" void kernel_launch(void* const* d_in, const int* in_sizes, int n_in,
                              void* d_out, int out_size, void* d_ws, size_t ws_size,
                              hipStream_t stream) {
  const float* x  = (const float*)d_in[0];
  const float* gw = (const float*)d_in[1];
  const float* w1 = (const float*)d_in[2];
  const float* w3 = (const float*)d_in[3];
  const float* w2 = (const float*)d_in[4];
  float* out = (float*)d_out;

  char* ws = (char*)d_ws;
  int*   counts   = (int*)(ws);
  int*   cursor   = (int*)(ws + 64);
  int*   offs     = (int*)(ws + 128);
  int*   tlist    = (int*)(ws + 192);              // 544 B
  int*   tlist2   = (int*)(ws + 768);              // 288 B
  int*   topi     = (int*)(ws + 2048);
  float* topw     = (float*)(ws + 2048 + 65536);
  int*   rowmap   = (int*)(ws + 2048 + 131072);
  float* roww     = (float*)(ws + 2048 + 196608);
  int*   rowoftok = (int*)(ws + 2048 + 262144);
  char*  big      = ws + 2048 + 327680;
  // Region plan: Bp [92.3 MB] holds (after gemm1): w2b [46.1] + y0 [33.5].
  // Xg [33.5] (dead after gemm1) holds y1. hbuf [92.3].
  bf16* Bp   = (bf16*)big;                                   // [8][5632][1024]
  bf16* w2b  = (bf16*)big;                                   // [8][1024][2816] (alias Bp)
  bf16* y0   = (bf16*)(big + 46137344);                      // [16384][1024] (alias Bp tail)
  bf16* Xg   = Bp + (size_t)E_NUM * NP * D_DIM;              // [16384][1024]
  bf16* y1   = Xg;                                           // alias (Xg dead after gemm1)
  bf16* hbuf = Xg + (size_t)NROWS * D_DIM;                   // [16384][2816]

  hipMemsetAsync((char*)d_out + (size_t)(out_size - 1) * sizeof(float), 0, sizeof(float), stream);
  hipMemsetAsync(ws, 0, 256, stream);   // counts, cursor

  int nbp = E_NUM * NP * 128;
  conv13_kernel<<<(nbp + 255) / 256, 256, 0, stream>>>(w1, w3, Bp);

  router_kernel<<<N_TOK / 4, 256, 0, stream>>>(x, gw, topi, topw, counts);
  tiles_kernel<<<1, 192, 0, stream>>>(counts, offs, tlist, tlist2);
  scatter_kernel<<<(NROWS + 255) / 256, 256, 0, stream>>>(topi, topw, offs, cursor, rowmap, roww, rowoftok);
  gather_kernel<<<NROWS / 4, 256, 0, stream>>>(x, rowmap, Xg);

  gemm1_kernel<<<MAXT256 * 44, 256, 0, stream>>>(Xg, Bp, counts, offs, tlist2, hbuf);

  int w2n = E_NUM * D_DIM * (HP / 8);
  conv_w2_kernel<<<(w2n + 255) / 256, 256, 0, stream>>>(w2, w2b);

  gemm2_kernel<<<MAXTILES * 16, 256, 0, stream>>>(hbuf, w2b, counts, offs, tlist, y0, y1);
  combine_kernel<<<N_TOK / 4, 256, 0, stream>>>(y0, y1, rowoftok, topw, out);
}

// Round 17
// 621.442 us; speedup vs baseline: 1.0618x; 1.0618x over previous
//
#include <hip/hip_runtime.h>
#include <hip/hip_bf16.h>

#define N_TOK 8192
#define D_DIM 1024
#define E_NUM 8
#define H_DIM 2730
#define HP    2816     // 22*128 padded h-cols
#define NP    5632     // 2*HP = interleaved B' rows
#define NROWS (N_TOK*2)
#define MAXTILES 136   // sum ceil(ne/128) <= 135
#define MAXT256  72    // sum ceil(ne/256) <= 71

typedef __bf16 bf16;
typedef __bf16 bf16x8 __attribute__((ext_vector_type(8)));
typedef __bf16 bf16x4 __attribute__((ext_vector_type(4)));
typedef float  f32x4  __attribute__((ext_vector_type(4)));

__device__ __forceinline__ void gload_lds16(const bf16* g, bf16* l) {
  __builtin_amdgcn_global_load_lds((const __attribute__((address_space(1))) void*)g,
                                   (__attribute__((address_space(3))) void*)l, 16, 0, 0);
}
#define VMCNT(n) asm volatile("s_waitcnt vmcnt(" #n ")" ::: "memory")
#define LGKM0()  asm volatile("s_waitcnt lgkmcnt(0)" ::: "memory")
#define BAR() __builtin_amdgcn_s_barrier()

// ---------- conv: build interleaved B' [e][5632][1024] bf16 ----------
__global__ void conv13_kernel(const float* __restrict__ w1, const float* __restrict__ w3,
                              bf16* __restrict__ Bp) {
  int i = blockIdx.x * blockDim.x + threadIdx.x;      // (e, r', c8)
  if (i >= E_NUM * NP * 128) return;
  int c8 = i & 127;
  int r  = (i >> 7) % NP;
  int e  = i / (NP * 128);
  int hc = ((r >> 5) << 4) + (r & 15);
  bf16x8 o;
  if (hc < H_DIM) {
    const float* s = (((r >> 4) & 1) ? w3 : w1) + ((long)e * H_DIM + hc) * D_DIM + c8 * 8;
    float4 a0 = ((const float4*)s)[0], a1 = ((const float4*)s)[1];
    o[0]=(bf16)a0.x; o[1]=(bf16)a0.y; o[2]=(bf16)a0.z; o[3]=(bf16)a0.w;
    o[4]=(bf16)a1.x; o[5]=(bf16)a1.y; o[6]=(bf16)a1.z; o[7]=(bf16)a1.w;
  } else {
    #pragma unroll
    for (int j = 0; j < 8; j++) o[j] = (bf16)0.f;
  }
  ((bf16x8*)Bp)[i] = o;
}

// r17: float2-vectorized (rows are 8B-aligned: H_DIM*4 = 10920 % 8 == 0)
__global__ void conv_w2_kernel(const float* __restrict__ src, bf16* __restrict__ dst) {
  int i = blockIdx.x * blockDim.x + threadIdx.x;      // row*(HP/8) + c8
  if (i >= E_NUM * D_DIM * (HP / 8)) return;
  int c8 = i % (HP / 8);
  int row = i / (HP / 8);
  int c = c8 * 8;
  const float* s = src + (long)row * H_DIM + c;
  bf16x8 o;
  if (c + 8 <= H_DIM) {
    const float2* s2 = (const float2*)s;
    float2 v0 = s2[0], v1 = s2[1], v2 = s2[2], v3 = s2[3];
    o[0]=(bf16)v0.x; o[1]=(bf16)v0.y; o[2]=(bf16)v1.x; o[3]=(bf16)v1.y;
    o[4]=(bf16)v2.x; o[5]=(bf16)v2.y; o[6]=(bf16)v3.x; o[7]=(bf16)v3.y;
  } else {
    #pragma unroll
    for (int j = 0; j < 8; j++) o[j] = (c + j < H_DIM) ? (bf16)s[j] : (bf16)0.f;
  }
  ((bf16x8*)dst)[i] = o;
}

// ---------------- router ----------------
__global__ void router_kernel(const float* __restrict__ x, const float* __restrict__ gw,
                              int* __restrict__ topi, float* __restrict__ topw,
                              int* __restrict__ counts) {
  int t = blockIdx.x * (blockDim.x >> 6) + (threadIdx.x >> 6);
  int lane = threadIdx.x & 63;
  if (t >= N_TOK) return;
  const float* xr = x + (long)t * D_DIM;
  float acc[E_NUM];
  #pragma unroll
  for (int e = 0; e < E_NUM; e++) acc[e] = 0.f;
  for (int j = 0; j < D_DIM / 64; j++) {
    float xv = xr[j * 64 + lane];
    #pragma unroll
    for (int e = 0; e < E_NUM; e++) acc[e] += xv * gw[e * D_DIM + j * 64 + lane];
  }
  #pragma unroll
  for (int e = 0; e < E_NUM; e++) {
    float v = acc[e];
    #pragma unroll
    for (int s = 32; s > 0; s >>= 1) v += __shfl_xor(v, s, 64);
    acc[e] = v;
  }
  if (lane == 0) {
    int b0 = -1, b1 = -1; float v0 = -1e30f, v1 = -1e30f;
    #pragma unroll
    for (int e = 0; e < E_NUM; e++) {
      float v = acc[e];
      if (v > v0) { v1 = v0; b1 = b0; v0 = v; b0 = e; }
      else if (v > v1) { v1 = v; b1 = e; }
    }
    float w0 = 1.f / (1.f + expf(v1 - v0));
    topi[t * 2] = b0; topi[t * 2 + 1] = b1;
    topw[t * 2] = w0; topw[t * 2 + 1] = 1.f - w0;
    atomicAdd(&counts[b0], 1); atomicAdd(&counts[b1], 1);
  }
}

// parallel tile-list build
__global__ void tiles_kernel(const int* __restrict__ counts, int* __restrict__ offs,
                             int* __restrict__ tlist, int* __restrict__ tlist2) {
  __shared__ int so[E_NUM + 1], sb[E_NUM + 1], sb2[E_NUM + 1];
  int t = threadIdx.x;
  if (t == 0) {
    int s = 0, b = 0, b2 = 0;
    for (int e = 0; e < E_NUM; e++) {
      so[e] = s; sb[e] = b; sb2[e] = b2;
      int ne = counts[e];
      s += ne; b += (ne + 127) >> 7; b2 += (ne + 255) >> 8;
    }
    so[E_NUM] = s; sb[E_NUM] = b; sb2[E_NUM] = b2;
  }
  __syncthreads();
  if (t <= E_NUM) offs[t] = so[t];
  for (int i = t; i < MAXTILES; i += blockDim.x) {
    int v = -1;
    #pragma unroll
    for (int e = 0; e < E_NUM; e++)
      if (i >= sb[e] && i < sb[e + 1]) v = (e << 8) | (i - sb[e]);
    tlist[i] = v;
  }
  for (int i = t; i < MAXT256; i += blockDim.x) {
    int v = -1;
    #pragma unroll
    for (int e = 0; e < E_NUM; e++)
      if (i >= sb2[e] && i < sb2[e + 1]) v = (e << 8) | (i - sb2[e]);
    tlist2[i] = v;
  }
}

// LDS-aggregated scatter — 8 global atomics/block
__global__ void scatter_kernel(const int* __restrict__ topi, const float* __restrict__ topw,
                               const int* __restrict__ offs, int* __restrict__ cursor,
                               int* __restrict__ rowmap, float* __restrict__ roww,
                               int* __restrict__ rowoftok) {
  __shared__ int hist[E_NUM], base[E_NUM];
  int i = blockIdx.x * blockDim.x + threadIdx.x;
  if (threadIdx.x < E_NUM) hist[threadIdx.x] = 0;
  __syncthreads();
  int e = 0, lpos = 0;
  bool act = (i < NROWS);
  if (act) { e = topi[i]; lpos = atomicAdd(&hist[e], 1); }
  __syncthreads();
  if (threadIdx.x < E_NUM) base[threadIdx.x] = atomicAdd(&cursor[threadIdx.x], hist[threadIdx.x]);
  __syncthreads();
  if (act) {
    int row = offs[e] + base[e] + lpos;
    rowmap[row] = i >> 1;
    roww[row] = topw[i];
    rowoftok[i] = row;
  }
}

__global__ void gather_kernel(const float* __restrict__ x, const int* __restrict__ rowmap,
                              bf16* __restrict__ Xg) {
  int r = blockIdx.x * (blockDim.x >> 6) + (threadIdx.x >> 6);
  int lane = threadIdx.x & 63;
  if (r >= NROWS) return;
  int t = rowmap[r];
  const float4* src = (const float4*)(x + (long)t * D_DIM);
  bf16x4* dst = (bf16x4*)(Xg + (long)r * D_DIM);
  #pragma unroll
  for (int j = 0; j < 4; j++) {
    float4 v = src[j * 64 + lane];
    bf16x4 o; o[0]=(bf16)v.x; o[1]=(bf16)v.y; o[2]=(bf16)v.z; o[3]=(bf16)v.w;
    dst[j * 64 + lane] = o;
  }
}

// combine (split-K2): out[t] = w0*(y0[r0]+y1[r0]) + w1*(y0[r1]+y1[r1])
__global__ void combine_kernel(const bf16* __restrict__ y0p, const bf16* __restrict__ y1p,
                               const int* __restrict__ rowoftok,
                               const float* __restrict__ topw, float* __restrict__ out) {
  int t = blockIdx.x * (blockDim.x >> 6) + (threadIdx.x >> 6);
  int lane = threadIdx.x & 63;
  if (t >= N_TOK) return;
  int r0 = rowoftok[t * 2], r1 = rowoftok[t * 2 + 1];
  float w0 = topw[t * 2], w1 = topw[t * 2 + 1];
  const bf16x8* a0 = (const bf16x8*)(y0p + (long)r0 * D_DIM);
  const bf16x8* a1 = (const bf16x8*)(y1p + (long)r0 * D_DIM);
  const bf16x8* b0 = (const bf16x8*)(y0p + (long)r1 * D_DIM);
  const bf16x8* b1 = (const bf16x8*)(y1p + (long)r1 * D_DIM);
  float* o = out + (long)t * D_DIM;
  #pragma unroll
  for (int j = 0; j < 2; j++) {
    int idx = j * 64 + lane;
    bf16x8 va0 = a0[idx], va1 = a1[idx], vb0 = b0[idx], vb1 = b1[idx];
    float4 v0, v1;
    v0.x = w0*((float)va0[0]+(float)va1[0]) + w1*((float)vb0[0]+(float)vb1[0]);
    v0.y = w0*((float)va0[1]+(float)va1[1]) + w1*((float)vb0[1]+(float)vb1[1]);
    v0.z = w0*((float)va0[2]+(float)va1[2]) + w1*((float)vb0[2]+(float)vb1[2]);
    v0.w = w0*((float)va0[3]+(float)va1[3]) + w1*((float)vb0[3]+(float)vb1[3]);
    v1.x = w0*((float)va0[4]+(float)va1[4]) + w1*((float)vb0[4]+(float)vb1[4]);
    v1.y = w0*((float)va0[5]+(float)va1[5]) + w1*((float)vb0[5]+(float)vb1[5]);
    v1.z = w0*((float)va0[6]+(float)va1[6]) + w1*((float)vb0[6]+(float)vb1[6]);
    v1.w = w0*((float)va0[7]+(float)va1[7]) + w1*((float)vb0[7]+(float)vb1[7]);
    float4* op = (float4*)(o + idx * 8);
    op[0] = v0; op[1] = v1;
  }
}

// ======== r17 (consolidation): gemm1 = r16 (paired bid map, FETCH 246 MB).
// gemm2 = r15 verbatim (split-K2 128Mx256N — best measured). ========

// ---------------- GEMM1: 256(M) x 128(B'cols), BK=32, 4 waves, 72 KB ----------
#define G1_STAGE(SB, T) do { \
    _Pragma("unroll") for (int L_ = 0; L_ < 4; L_++) \
      gload_lds16(aS[L_] + (T) * 32, smem + (SB) + w * 2048 + L_ * 512); \
    _Pragma("unroll") for (int L_ = 0; L_ < 2; L_++) \
      gload_lds16(bS[L_] + (T) * 32, smem + (SB) + 8192 + w * 1024 + L_ * 512); \
  } while (0)

#define G1_READ0(SB) do { \
    _Pragma("unroll") for (int m_ = 0; m_ < 4; m_++) \
      af[m_] = *(const bf16x8*)&smem[(SB) + (w * 64 + m_ * 16 + fr) * 32 + qp]; \
    _Pragma("unroll") for (int q_ = 0; q_ < 4; q_++) \
      bf0[q_] = *(const bf16x8*)&smem[(SB) + 8192 + (q_ * 16 + fr) * 32 + qp]; \
  } while (0)

#define G1_MFMA0() do { __builtin_amdgcn_s_setprio(1); \
    _Pragma("unroll") for (int m_ = 0; m_ < 4; m_++) \
    _Pragma("unroll") for (int q_ = 0; q_ < 4; q_++) \
      acc[m_][q_] = __builtin_amdgcn_mfma_f32_16x16x32_bf16(af[m_], bf0[q_], acc[m_][q_], 0, 0, 0); \
    __builtin_amdgcn_s_setprio(0); } while (0)

#define G1_READ1(SB) do { \
    _Pragma("unroll") for (int q_ = 0; q_ < 4; q_++) \
      bf1[q_] = *(const bf16x8*)&smem[(SB) + 8192 + ((q_ + 4) * 16 + fr) * 32 + qp]; \
  } while (0)

#define G1_MFMA1() do { __builtin_amdgcn_s_setprio(1); \
    _Pragma("unroll") for (int m_ = 0; m_ < 4; m_++) \
    _Pragma("unroll") for (int q_ = 0; q_ < 4; q_++) \
      acc[m_][q_ + 4] = __builtin_amdgcn_mfma_f32_16x16x32_bf16(af[m_], bf1[q_], acc[m_][q_ + 4], 0, 0, 0); \
    __builtin_amdgcn_s_setprio(0); } while (0)

__global__ __launch_bounds__(256, 2) void gemm1_kernel(
    const bf16* __restrict__ Xg, const bf16* __restrict__ Bp,
    const int* __restrict__ counts, const int* __restrict__ offs,
    const int* __restrict__ tlist2, bf16* __restrict__ h) {
  int bid = blockIdx.x;
  int pair = bid / 88, within = bid - pair * 88;
  int col = within >> 1, tp = within & 1;             // tp innermost: B-panel pairing
  int tile = pair * 2 + tp;
  int te = tlist2[tile];
  if (te < 0) return;
  int e = te >> 8, tm = te & 255;
  int ne = counts[e];
  int row_base = offs[e];
  int n0 = col * 128;                                 // B'-col base

  __shared__ bf16 smem[3 * 12288];                    // 72 KB: [slot][A 8192 | B 4096]
  int tid = threadIdx.x, w = tid >> 6, lane = tid & 63;
  int fr = lane & 15, hi = lane >> 4;
  int qp = (hi ^ ((fr >> 1) & 3)) * 8;
  int srcq = ((lane & 3) ^ ((lane >> 3) & 3)) * 8;
  int srow = lane >> 2;

  f32x4 acc[4][8];
  #pragma unroll
  for (int m = 0; m < 4; m++)
    #pragma unroll
    for (int q = 0; q < 8; q++) acc[m][q] = (f32x4)0.f;

  const bf16* Bpe = Bp + (long)e * NP * D_DIM;
  const bf16* aS[4];
  const bf16* bS[2];
  #pragma unroll
  for (int L = 0; L < 4; L++) {
    int ra = row_base + min(tm * 256 + w * 64 + L * 16 + srow, ne - 1);
    aS[L] = Xg + (long)ra * D_DIM + srcq;
  }
  #pragma unroll
  for (int L = 0; L < 2; L++) {
    int rb = n0 + w * 32 + L * 16 + srow;
    bS[L] = Bpe + (long)rb * D_DIM + srcq;
  }

  bf16x8 af[4], bf0[4], bf1[4];

  G1_STAGE(0, 0); G1_STAGE(12288, 1);
  VMCNT(6); BAR();

  int sbC = 0, sbS = 24576;
  for (int t = 0; t < 30; t++) {                      // tiles 0..29; stage 2..31
    G1_READ0(sbC);
    G1_STAGE(sbS, t + 2);
    BAR();
    G1_MFMA0();
    G1_READ1(sbC);
    G1_MFMA1();
    LGKM0(); VMCNT(6); BAR();
    sbC += 12288; if (sbC > 24576) sbC = 0;
    sbS += 12288; if (sbS > 24576) sbS = 0;
  }
  { G1_READ0(sbC); BAR(); G1_MFMA0(); G1_READ1(sbC); G1_MFMA1(); LGKM0(); VMCNT(0); BAR();
    sbC += 12288; if (sbC > 24576) sbC = 0; }
  { G1_READ0(sbC); G1_MFMA0(); G1_READ1(sbC); G1_MFMA1(); }

  // epilogue: q=2p -> gate, q=2p+1 -> up (B' 16-row interleave); h-col base n0/2
  int crow4 = hi * 4;
  #pragma unroll
  for (int m = 0; m < 4; m++)
    #pragma unroll
    for (int j = 0; j < 4; j++) {
      int rloc = tm * 256 + w * 64 + m * 16 + crow4 + j;
      if (rloc < ne) {
        long hrow = (long)(row_base + rloc) * HP;
        #pragma unroll
        for (int p = 0; p < 4; p++) {
          int col2 = (n0 >> 1) + p * 16 + fr;
          float g = acc[m][2 * p][j], u = acc[m][2 * p + 1][j];
          h[hrow + col2] = (bf16)((g / (1.f + __expf(-g))) * u);
        }
      }
    }
}

// -------- GEMM2: 128(M) x 256(N), BK=32, 4 waves, 72 KB; SPLIT-K2 --------
#define G2_STAGE(SB, T) do { \
    _Pragma("unroll") for (int L_ = 0; L_ < 2; L_++) \
      gload_lds16(aS[L_] + (T) * 32, smem2 + (SB) + w * 1024 + L_ * 512); \
    _Pragma("unroll") for (int L_ = 0; L_ < 4; L_++) \
      gload_lds16(bS[L_] + (T) * 32, smem2 + (SB) + 4096 + (L_ * 4 + w) * 512); \
  } while (0)

#define G2_READ0(SB) do { \
    _Pragma("unroll") for (int m_ = 0; m_ < 4; m_++) \
      af[m_] = *(const bf16x8*)&smem2[(SB) + (wr * 64 + m_ * 16 + fr) * 32 + qp]; \
    _Pragma("unroll") for (int n_ = 0; n_ < 4; n_++) \
      bf0[n_] = *(const bf16x8*)&smem2[(SB) + 4096 + (wc * 128 + n_ * 16 + fr) * 32 + qp]; \
  } while (0)

#define G2_MFMA0() do { __builtin_amdgcn_s_setprio(1); \
    _Pragma("unroll") for (int m_ = 0; m_ < 4; m_++) \
    _Pragma("unroll") for (int n_ = 0; n_ < 4; n_++) \
      acc[m_][n_] = __builtin_amdgcn_mfma_f32_16x16x32_bf16(af[m_], bf0[n_], acc[m_][n_], 0, 0, 0); \
    __builtin_amdgcn_s_setprio(0); } while (0)

#define G2_READ1(SB) do { \
    _Pragma("unroll") for (int n_ = 0; n_ < 4; n_++) \
      bf1[n_] = *(const bf16x8*)&smem2[(SB) + 4096 + (wc * 128 + (n_ + 4) * 16 + fr) * 32 + qp]; \
  } while (0)

#define G2_MFMA1() do { __builtin_amdgcn_s_setprio(1); \
    _Pragma("unroll") for (int m_ = 0; m_ < 4; m_++) \
    _Pragma("unroll") for (int n_ = 0; n_ < 4; n_++) \
      acc[m_][n_ + 4] = __builtin_amdgcn_mfma_f32_16x16x32_bf16(af[m_], bf1[n_], acc[m_][n_ + 4], 0, 0, 0); \
    __builtin_amdgcn_s_setprio(0); } while (0)

__global__ __launch_bounds__(256, 2) void gemm2_kernel(
    const bf16* __restrict__ h, const bf16* __restrict__ w2b,
    const int* __restrict__ counts, const int* __restrict__ offs,
    const int* __restrict__ tlist, bf16* __restrict__ y0p, bf16* __restrict__ y1p) {
  int bid = blockIdx.x;
  int tile = bid >> 3, col = (bid >> 1) & 3, ks = bid & 1;  // col-fastest, ks innermost
  int te = tlist[tile];
  if (te < 0) return;
  int e = te >> 8, tm = te & 255;
  int ne = counts[e];
  int row_base = offs[e];
  int n0 = col * 256;
  int k0 = ks * 1408;                                 // K-half base (44 tiles x 32)

  __shared__ bf16 smem2[3 * 12288];                   // 72 KB: [slot][A 4096 | B 8192]
  int tid = threadIdx.x, w = tid >> 6, lane = tid & 63;
  int wr = w >> 1, wc = w & 1;
  int fr = lane & 15, hi = lane >> 4;
  int qp = (hi ^ ((fr >> 1) & 3)) * 8;
  int srcq = ((lane & 3) ^ ((lane >> 3) & 3)) * 8;
  int srow = lane >> 2;

  f32x4 acc[4][8];
  #pragma unroll
  for (int m = 0; m < 4; m++)
    #pragma unroll
    for (int n = 0; n < 8; n++) acc[m][n] = (f32x4)0.f;

  const bf16* w2e = w2b + (long)e * D_DIM * HP;
  const bf16* aS[2];
  const bf16* bS[4];
  #pragma unroll
  for (int L = 0; L < 2; L++) {
    int ra = row_base + min(tm * 128 + w * 32 + L * 16 + srow, ne - 1);
    aS[L] = h + (long)ra * HP + k0 + srcq;
  }
  #pragma unroll
  for (int L = 0; L < 4; L++) {
    int rb = n0 + (L * 4 + w) * 16 + srow;
    bS[L] = w2e + (long)rb * HP + k0 + srcq;
  }

  bf16x8 af[4], bf0[4], bf1[4];

  G2_STAGE(0, 0); G2_STAGE(12288, 1);
  VMCNT(6); BAR();

  int sbC = 0, sbS = 24576;
  for (int t = 0; t < 42; t++) {                      // tiles 0..41; stage 2..43
    G2_READ0(sbC);
    G2_STAGE(sbS, t + 2);
    BAR();
    G2_MFMA0();
    G2_READ1(sbC);
    G2_MFMA1();
    LGKM0(); VMCNT(6); BAR();
    sbC += 12288; if (sbC > 24576) sbC = 0;
    sbS += 12288; if (sbS > 24576) sbS = 0;
  }
  { G2_READ0(sbC); BAR(); G2_MFMA0(); G2_READ1(sbC); G2_MFMA1(); LGKM0(); VMCNT(0); BAR();
    sbC += 12288; if (sbC > 24576) sbC = 0; }
  { G2_READ0(sbC); G2_MFMA0(); G2_READ1(sbC); G2_MFMA1(); }

  bf16* y = ks ? y1p : y0p;
  int crow4 = hi * 4;
  #pragma unroll
  for (int m = 0; m < 4; m++)
    #pragma unroll
    for (int j = 0; j < 4; j++) {
      int rloc = tm * 128 + wr * 64 + m * 16 + crow4 + j;
      if (rloc < ne) {
        long yrow = (long)(row_base + rloc) * D_DIM;
        #pragma unroll
        for (int n = 0; n < 8; n++) {
          int col2 = n0 + wc * 128 + n * 16 + fr;
          y[yrow + col2] = (bf16)acc[m][n][j];
        }
      }
    }
}

extern "C" void kernel_launch(void* const* d_in, const int* in_sizes, int n_in,
                              void* d_out, int out_size, void* d_ws, size_t ws_size,
                              hipStream_t stream) {
  const float* x  = (const float*)d_in[0];
  const float* gw = (const float*)d_in[1];
  const float* w1 = (const float*)d_in[2];
  const float* w3 = (const float*)d_in[3];
  const float* w2 = (const float*)d_in[4];
  float* out = (float*)d_out;

  char* ws = (char*)d_ws;
  int*   counts   = (int*)(ws);
  int*   cursor   = (int*)(ws + 64);
  int*   offs     = (int*)(ws + 128);
  int*   tlist    = (int*)(ws + 192);              // 544 B
  int*   tlist2   = (int*)(ws + 768);              // 288 B
  int*   topi     = (int*)(ws + 2048);
  float* topw     = (float*)(ws + 2048 + 65536);
  int*   rowmap   = (int*)(ws + 2048 + 131072);
  float* roww     = (float*)(ws + 2048 + 196608);
  int*   rowoftok = (int*)(ws + 2048 + 262144);
  char*  big      = ws + 2048 + 327680;
  // Region plan: Bp [92.3 MB] holds (after gemm1): w2b [46.1] + y0 [33.5].
  // Xg [33.5] (dead after gemm1) holds y1. hbuf [92.3].
  bf16* Bp   = (bf16*)big;                                   // [8][5632][1024]
  bf16* w2b  = (bf16*)big;                                   // [8][1024][2816] (alias Bp)
  bf16* y0   = (bf16*)(big + 46137344);                      // [16384][1024] (alias Bp tail)
  bf16* Xg   = Bp + (size_t)E_NUM * NP * D_DIM;              // [16384][1024]
  bf16* y1   = Xg;                                           // alias (Xg dead after gemm1)
  bf16* hbuf = Xg + (size_t)NROWS * D_DIM;                   // [16384][2816]

  hipMemsetAsync((char*)d_out + (size_t)(out_size - 1) * sizeof(float), 0, sizeof(float), stream);
  hipMemsetAsync(ws, 0, 256, stream);   // counts, cursor

  int nbp = E_NUM * NP * 128;
  conv13_kernel<<<(nbp + 255) / 256, 256, 0, stream>>>(w1, w3, Bp);

  router_kernel<<<N_TOK / 4, 256, 0, stream>>>(x, gw, topi, topw, counts);
  tiles_kernel<<<1, 192, 0, stream>>>(counts, offs, tlist, tlist2);
  scatter_kernel<<<(NROWS + 255) / 256, 256, 0, stream>>>(topi, topw, offs, cursor, rowmap, roww, rowoftok);
  gather_kernel<<<NROWS / 4, 256, 0, stream>>>(x, rowmap, Xg);

  gemm1_kernel<<<MAXT256 * 44, 256, 0, stream>>>(Xg, Bp, counts, offs, tlist2, hbuf);

  int w2n = E_NUM * D_DIM * (HP / 8);
  conv_w2_kernel<<<(w2n + 255) / 256, 256, 0, stream>>>(w2, w2b);

  gemm2_kernel<<<MAXTILES * 8, 256, 0, stream>>>(hbuf, w2b, counts, offs, tlist, y0, y1);
  combine_kernel<<<N_TOK / 4, 256, 0, stream>>>(y0, y1, rowoftok, topw, out);
}

// Round 18
// 618.019 us; speedup vs baseline: 1.0677x; 1.0055x over previous
//
#include <hip/hip_runtime.h>
#include <hip/hip_bf16.h>

#define N_TOK 8192
#define D_DIM 1024
#define E_NUM 8
#define H_DIM 2730
#define HP    2816     // 22*128 padded h-cols
#define NP    5632     // 2*HP = interleaved B' rows
#define NROWS (N_TOK*2)
#define MAXTILES 136   // sum ceil(ne/128) <= 135
#define MAXT256  72    // sum ceil(ne/256) <= 71

typedef __bf16 bf16;
typedef __bf16 bf16x8 __attribute__((ext_vector_type(8)));
typedef __bf16 bf16x4 __attribute__((ext_vector_type(4)));
typedef float  f32x4  __attribute__((ext_vector_type(4)));

__device__ __forceinline__ void gload_lds16(const bf16* g, bf16* l) {
  __builtin_amdgcn_global_load_lds((const __attribute__((address_space(1))) void*)g,
                                   (__attribute__((address_space(3))) void*)l, 16, 0, 0);
}
#define VMCNT(n) asm volatile("s_waitcnt vmcnt(" #n ")" ::: "memory")
#define LGKM0()  asm volatile("s_waitcnt lgkmcnt(0)" ::: "memory")
#define BAR() __builtin_amdgcn_s_barrier()

// ---------- conv: build interleaved B' [e][5632][1024] bf16 ----------
__global__ void conv13_kernel(const float* __restrict__ w1, const float* __restrict__ w3,
                              bf16* __restrict__ Bp) {
  int i = blockIdx.x * blockDim.x + threadIdx.x;      // (e, r', c8)
  if (i >= E_NUM * NP * 128) return;
  int c8 = i & 127;
  int r  = (i >> 7) % NP;
  int e  = i / (NP * 128);
  int hc = ((r >> 5) << 4) + (r & 15);
  bf16x8 o;
  if (hc < H_DIM) {
    const float* s = (((r >> 4) & 1) ? w3 : w1) + ((long)e * H_DIM + hc) * D_DIM + c8 * 8;
    float4 a0 = ((const float4*)s)[0], a1 = ((const float4*)s)[1];
    o[0]=(bf16)a0.x; o[1]=(bf16)a0.y; o[2]=(bf16)a0.z; o[3]=(bf16)a0.w;
    o[4]=(bf16)a1.x; o[5]=(bf16)a1.y; o[6]=(bf16)a1.z; o[7]=(bf16)a1.w;
  } else {
    #pragma unroll
    for (int j = 0; j < 8; j++) o[j] = (bf16)0.f;
  }
  ((bf16x8*)Bp)[i] = o;
}

// float2-vectorized (rows are 8B-aligned: H_DIM*4 = 10920 % 8 == 0)
__global__ void conv_w2_kernel(const float* __restrict__ src, bf16* __restrict__ dst) {
  int i = blockIdx.x * blockDim.x + threadIdx.x;      // row*(HP/8) + c8
  if (i >= E_NUM * D_DIM * (HP / 8)) return;
  int c8 = i % (HP / 8);
  int row = i / (HP / 8);
  int c = c8 * 8;
  const float* s = src + (long)row * H_DIM + c;
  bf16x8 o;
  if (c + 8 <= H_DIM) {
    const float2* s2 = (const float2*)s;
    float2 v0 = s2[0], v1 = s2[1], v2 = s2[2], v3 = s2[3];
    o[0]=(bf16)v0.x; o[1]=(bf16)v0.y; o[2]=(bf16)v1.x; o[3]=(bf16)v1.y;
    o[4]=(bf16)v2.x; o[5]=(bf16)v2.y; o[6]=(bf16)v3.x; o[7]=(bf16)v3.y;
  } else {
    #pragma unroll
    for (int j = 0; j < 8; j++) o[j] = (c + j < H_DIM) ? (bf16)s[j] : (bf16)0.f;
  }
  ((bf16x8*)dst)[i] = o;
}

// ---------------- router (r18: float4-vectorized x/gw loads) ----------------
__global__ void router_kernel(const float* __restrict__ x, const float* __restrict__ gw,
                              int* __restrict__ topi, float* __restrict__ topw,
                              int* __restrict__ counts) {
  int t = blockIdx.x * (blockDim.x >> 6) + (threadIdx.x >> 6);
  int lane = threadIdx.x & 63;
  if (t >= N_TOK) return;
  const float4* xr = (const float4*)(x + (long)t * D_DIM);
  float acc[E_NUM];
  #pragma unroll
  for (int e = 0; e < E_NUM; e++) acc[e] = 0.f;
  #pragma unroll
  for (int j = 0; j < D_DIM / 256; j++) {             // 4 iters of float4
    float4 xv = xr[j * 64 + lane];
    #pragma unroll
    for (int e = 0; e < E_NUM; e++) {
      float4 gv = ((const float4*)(gw + e * D_DIM))[j * 64 + lane];
      acc[e] += xv.x * gv.x + xv.y * gv.y + xv.z * gv.z + xv.w * gv.w;
    }
  }
  #pragma unroll
  for (int e = 0; e < E_NUM; e++) {
    float v = acc[e];
    #pragma unroll
    for (int s = 32; s > 0; s >>= 1) v += __shfl_xor(v, s, 64);
    acc[e] = v;
  }
  if (lane == 0) {
    int b0 = -1, b1 = -1; float v0 = -1e30f, v1 = -1e30f;
    #pragma unroll
    for (int e = 0; e < E_NUM; e++) {
      float v = acc[e];
      if (v > v0) { v1 = v0; b1 = b0; v0 = v; b0 = e; }
      else if (v > v1) { v1 = v; b1 = e; }
    }
    float w0 = 1.f / (1.f + expf(v1 - v0));
    topi[t * 2] = b0; topi[t * 2 + 1] = b1;
    topw[t * 2] = w0; topw[t * 2 + 1] = 1.f - w0;
    atomicAdd(&counts[b0], 1); atomicAdd(&counts[b1], 1);
  }
}

// parallel tile-list build
__global__ void tiles_kernel(const int* __restrict__ counts, int* __restrict__ offs,
                             int* __restrict__ tlist, int* __restrict__ tlist2) {
  __shared__ int so[E_NUM + 1], sb[E_NUM + 1], sb2[E_NUM + 1];
  int t = threadIdx.x;
  if (t == 0) {
    int s = 0, b = 0, b2 = 0;
    for (int e = 0; e < E_NUM; e++) {
      so[e] = s; sb[e] = b; sb2[e] = b2;
      int ne = counts[e];
      s += ne; b += (ne + 127) >> 7; b2 += (ne + 255) >> 8;
    }
    so[E_NUM] = s; sb[E_NUM] = b; sb2[E_NUM] = b2;
  }
  __syncthreads();
  if (t <= E_NUM) offs[t] = so[t];
  for (int i = t; i < MAXTILES; i += blockDim.x) {
    int v = -1;
    #pragma unroll
    for (int e = 0; e < E_NUM; e++)
      if (i >= sb[e] && i < sb[e + 1]) v = (e << 8) | (i - sb[e]);
    tlist[i] = v;
  }
  for (int i = t; i < MAXT256; i += blockDim.x) {
    int v = -1;
    #pragma unroll
    for (int e = 0; e < E_NUM; e++)
      if (i >= sb2[e] && i < sb2[e + 1]) v = (e << 8) | (i - sb2[e]);
    tlist2[i] = v;
  }
}

// r18: fused scatter+gather — 64 assignments/block; LDS histogram (8 global
// atomics/block); in-block x-row copy. rowmap/roww arrays eliminated.
__global__ void scatter_gather_kernel(const int* __restrict__ topi, const float* __restrict__ x,
                                      const int* __restrict__ offs, int* __restrict__ cursor,
                                      int* __restrict__ rowoftok, bf16* __restrict__ Xg) {
  __shared__ int hist[E_NUM], base[E_NUM];
  __shared__ int srow[64];
  int i0 = blockIdx.x * 64;
  int tid = threadIdx.x;
  if (tid < E_NUM) hist[tid] = 0;
  __syncthreads();
  int e = 0, lpos = 0;
  if (tid < 64) { e = topi[i0 + tid]; lpos = atomicAdd(&hist[e], 1); }
  __syncthreads();
  if (tid < E_NUM) base[tid] = atomicAdd(&cursor[tid], hist[tid]);
  __syncthreads();
  if (tid < 64) {
    int row = offs[e] + base[e] + lpos;
    srow[tid] = row;
    rowoftok[i0 + tid] = row;
  }
  __syncthreads();
  int wv = tid >> 6, lane = tid & 63;
  for (int k = wv; k < 64; k += 4) {
    int tok = (i0 + k) >> 1;
    int row = srow[k];
    const float4* src = (const float4*)(x + (long)tok * D_DIM);
    bf16x4* dst = (bf16x4*)(Xg + (long)row * D_DIM);
    #pragma unroll
    for (int j = 0; j < 4; j++) {
      float4 v = src[j * 64 + lane];
      bf16x4 o; o[0]=(bf16)v.x; o[1]=(bf16)v.y; o[2]=(bf16)v.z; o[3]=(bf16)v.w;
      dst[j * 64 + lane] = o;
    }
  }
}

// combine (split-K2): out[t] = w0*(y0[r0]+y1[r0]) + w1*(y0[r1]+y1[r1])
__global__ void combine_kernel(const bf16* __restrict__ y0p, const bf16* __restrict__ y1p,
                               const int* __restrict__ rowoftok,
                               const float* __restrict__ topw, float* __restrict__ out) {
  int t = blockIdx.x * (blockDim.x >> 6) + (threadIdx.x >> 6);
  int lane = threadIdx.x & 63;
  if (t >= N_TOK) return;
  int r0 = rowoftok[t * 2], r1 = rowoftok[t * 2 + 1];
  float w0 = topw[t * 2], w1 = topw[t * 2 + 1];
  const bf16x8* a0 = (const bf16x8*)(y0p + (long)r0 * D_DIM);
  const bf16x8* a1 = (const bf16x8*)(y1p + (long)r0 * D_DIM);
  const bf16x8* b0 = (const bf16x8*)(y0p + (long)r1 * D_DIM);
  const bf16x8* b1 = (const bf16x8*)(y1p + (long)r1 * D_DIM);
  float* o = out + (long)t * D_DIM;
  #pragma unroll
  for (int j = 0; j < 2; j++) {
    int idx = j * 64 + lane;
    bf16x8 va0 = a0[idx], va1 = a1[idx], vb0 = b0[idx], vb1 = b1[idx];
    float4 v0, v1;
    v0.x = w0*((float)va0[0]+(float)va1[0]) + w1*((float)vb0[0]+(float)vb1[0]);
    v0.y = w0*((float)va0[1]+(float)va1[1]) + w1*((float)vb0[1]+(float)vb1[1]);
    v0.z = w0*((float)va0[2]+(float)va1[2]) + w1*((float)vb0[2]+(float)vb1[2]);
    v0.w = w0*((float)va0[3]+(float)va1[3]) + w1*((float)vb0[3]+(float)vb1[3]);
    v1.x = w0*((float)va0[4]+(float)va1[4]) + w1*((float)vb0[4]+(float)vb1[4]);
    v1.y = w0*((float)va0[5]+(float)va1[5]) + w1*((float)vb0[5]+(float)vb1[5]);
    v1.z = w0*((float)va0[6]+(float)va1[6]) + w1*((float)vb0[6]+(float)vb1[6]);
    v1.w = w0*((float)va0[7]+(float)va1[7]) + w1*((float)vb0[7]+(float)vb1[7]);
    float4* op = (float4*)(o + idx * 8);
    op[0] = v0; op[1] = v1;
  }
}

// ======== r18: GEMMs verbatim from r17 (best measured: 621.4 us). ========

// ---------------- GEMM1: 256(M) x 128(B'cols), BK=32, 4 waves, 72 KB ----------
#define G1_STAGE(SB, T) do { \
    _Pragma("unroll") for (int L_ = 0; L_ < 4; L_++) \
      gload_lds16(aS[L_] + (T) * 32, smem + (SB) + w * 2048 + L_ * 512); \
    _Pragma("unroll") for (int L_ = 0; L_ < 2; L_++) \
      gload_lds16(bS[L_] + (T) * 32, smem + (SB) + 8192 + w * 1024 + L_ * 512); \
  } while (0)

#define G1_READ0(SB) do { \
    _Pragma("unroll") for (int m_ = 0; m_ < 4; m_++) \
      af[m_] = *(const bf16x8*)&smem[(SB) + (w * 64 + m_ * 16 + fr) * 32 + qp]; \
    _Pragma("unroll") for (int q_ = 0; q_ < 4; q_++) \
      bf0[q_] = *(const bf16x8*)&smem[(SB) + 8192 + (q_ * 16 + fr) * 32 + qp]; \
  } while (0)

#define G1_MFMA0() do { __builtin_amdgcn_s_setprio(1); \
    _Pragma("unroll") for (int m_ = 0; m_ < 4; m_++) \
    _Pragma("unroll") for (int q_ = 0; q_ < 4; q_++) \
      acc[m_][q_] = __builtin_amdgcn_mfma_f32_16x16x32_bf16(af[m_], bf0[q_], acc[m_][q_], 0, 0, 0); \
    __builtin_amdgcn_s_setprio(0); } while (0)

#define G1_READ1(SB) do { \
    _Pragma("unroll") for (int q_ = 0; q_ < 4; q_++) \
      bf1[q_] = *(const bf16x8*)&smem[(SB) + 8192 + ((q_ + 4) * 16 + fr) * 32 + qp]; \
  } while (0)

#define G1_MFMA1() do { __builtin_amdgcn_s_setprio(1); \
    _Pragma("unroll") for (int m_ = 0; m_ < 4; m_++) \
    _Pragma("unroll") for (int q_ = 0; q_ < 4; q_++) \
      acc[m_][q_ + 4] = __builtin_amdgcn_mfma_f32_16x16x32_bf16(af[m_], bf1[q_], acc[m_][q_ + 4], 0, 0, 0); \
    __builtin_amdgcn_s_setprio(0); } while (0)

__global__ __launch_bounds__(256, 2) void gemm1_kernel(
    const bf16* __restrict__ Xg, const bf16* __restrict__ Bp,
    const int* __restrict__ counts, const int* __restrict__ offs,
    const int* __restrict__ tlist2, bf16* __restrict__ h) {
  int bid = blockIdx.x;
  int pair = bid / 88, within = bid - pair * 88;
  int col = within >> 1, tp = within & 1;             // tp innermost: B-panel pairing
  int tile = pair * 2 + tp;
  int te = tlist2[tile];
  if (te < 0) return;
  int e = te >> 8, tm = te & 255;
  int ne = counts[e];
  int row_base = offs[e];
  int n0 = col * 128;                                 // B'-col base

  __shared__ bf16 smem[3 * 12288];                    // 72 KB: [slot][A 8192 | B 4096]
  int tid = threadIdx.x, w = tid >> 6, lane = tid & 63;
  int fr = lane & 15, hi = lane >> 4;
  int qp = (hi ^ ((fr >> 1) & 3)) * 8;
  int srcq = ((lane & 3) ^ ((lane >> 3) & 3)) * 8;
  int srow = lane >> 2;

  f32x4 acc[4][8];
  #pragma unroll
  for (int m = 0; m < 4; m++)
    #pragma unroll
    for (int q = 0; q < 8; q++) acc[m][q] = (f32x4)0.f;

  const bf16* Bpe = Bp + (long)e * NP * D_DIM;
  const bf16* aS[4];
  const bf16* bS[2];
  #pragma unroll
  for (int L = 0; L < 4; L++) {
    int ra = row_base + min(tm * 256 + w * 64 + L * 16 + srow, ne - 1);
    aS[L] = Xg + (long)ra * D_DIM + srcq;
  }
  #pragma unroll
  for (int L = 0; L < 2; L++) {
    int rb = n0 + w * 32 + L * 16 + srow;
    bS[L] = Bpe + (long)rb * D_DIM + srcq;
  }

  bf16x8 af[4], bf0[4], bf1[4];

  G1_STAGE(0, 0); G1_STAGE(12288, 1);
  VMCNT(6); BAR();

  int sbC = 0, sbS = 24576;
  for (int t = 0; t < 30; t++) {                      // tiles 0..29; stage 2..31
    G1_READ0(sbC);
    G1_STAGE(sbS, t + 2);
    BAR();
    G1_MFMA0();
    G1_READ1(sbC);
    G1_MFMA1();
    LGKM0(); VMCNT(6); BAR();
    sbC += 12288; if (sbC > 24576) sbC = 0;
    sbS += 12288; if (sbS > 24576) sbS = 0;
  }
  { G1_READ0(sbC); BAR(); G1_MFMA0(); G1_READ1(sbC); G1_MFMA1(); LGKM0(); VMCNT(0); BAR();
    sbC += 12288; if (sbC > 24576) sbC = 0; }
  { G1_READ0(sbC); G1_MFMA0(); G1_READ1(sbC); G1_MFMA1(); }

  // epilogue: q=2p -> gate, q=2p+1 -> up (B' 16-row interleave); h-col base n0/2
  int crow4 = hi * 4;
  #pragma unroll
  for (int m = 0; m < 4; m++)
    #pragma unroll
    for (int j = 0; j < 4; j++) {
      int rloc = tm * 256 + w * 64 + m * 16 + crow4 + j;
      if (rloc < ne) {
        long hrow = (long)(row_base + rloc) * HP;
        #pragma unroll
        for (int p = 0; p < 4; p++) {
          int col2 = (n0 >> 1) + p * 16 + fr;
          float g = acc[m][2 * p][j], u = acc[m][2 * p + 1][j];
          h[hrow + col2] = (bf16)((g / (1.f + __expf(-g))) * u);
        }
      }
    }
}

// -------- GEMM2: 128(M) x 256(N), BK=32, 4 waves, 72 KB; SPLIT-K2 --------
#define G2_STAGE(SB, T) do { \
    _Pragma("unroll") for (int L_ = 0; L_ < 2; L_++) \
      gload_lds16(aS[L_] + (T) * 32, smem2 + (SB) + w * 1024 + L_ * 512); \
    _Pragma("unroll") for (int L_ = 0; L_ < 4; L_++) \
      gload_lds16(bS[L_] + (T) * 32, smem2 + (SB) + 4096 + (L_ * 4 + w) * 512); \
  } while (0)

#define G2_READ0(SB) do { \
    _Pragma("unroll") for (int m_ = 0; m_ < 4; m_++) \
      af[m_] = *(const bf16x8*)&smem2[(SB) + (wr * 64 + m_ * 16 + fr) * 32 + qp]; \
    _Pragma("unroll") for (int n_ = 0; n_ < 4; n_++) \
      bf0[n_] = *(const bf16x8*)&smem2[(SB) + 4096 + (wc * 128 + n_ * 16 + fr) * 32 + qp]; \
  } while (0)

#define G2_MFMA0() do { __builtin_amdgcn_s_setprio(1); \
    _Pragma("unroll") for (int m_ = 0; m_ < 4; m_++) \
    _Pragma("unroll") for (int n_ = 0; n_ < 4; n_++) \
      acc[m_][n_] = __builtin_amdgcn_mfma_f32_16x16x32_bf16(af[m_], bf0[n_], acc[m_][n_], 0, 0, 0); \
    __builtin_amdgcn_s_setprio(0); } while (0)

#define G2_READ1(SB) do { \
    _Pragma("unroll") for (int n_ = 0; n_ < 4; n_++) \
      bf1[n_] = *(const bf16x8*)&smem2[(SB) + 4096 + (wc * 128 + (n_ + 4) * 16 + fr) * 32 + qp]; \
  } while (0)

#define G2_MFMA1() do { __builtin_amdgcn_s_setprio(1); \
    _Pragma("unroll") for (int m_ = 0; m_ < 4; m_++) \
    _Pragma("unroll") for (int n_ = 0; n_ < 4; n_++) \
      acc[m_][n_ + 4] = __builtin_amdgcn_mfma_f32_16x16x32_bf16(af[m_], bf1[n_], acc[m_][n_ + 4], 0, 0, 0); \
    __builtin_amdgcn_s_setprio(0); } while (0)

__global__ __launch_bounds__(256, 2) void gemm2_kernel(
    const bf16* __restrict__ h, const bf16* __restrict__ w2b,
    const int* __restrict__ counts, const int* __restrict__ offs,
    const int* __restrict__ tlist, bf16* __restrict__ y0p, bf16* __restrict__ y1p) {
  int bid = blockIdx.x;
  int tile = bid >> 3, col = (bid >> 1) & 3, ks = bid & 1;  // col-fastest, ks innermost
  int te = tlist[tile];
  if (te < 0) return;
  int e = te >> 8, tm = te & 255;
  int ne = counts[e];
  int row_base = offs[e];
  int n0 = col * 256;
  int k0 = ks * 1408;                                 // K-half base (44 tiles x 32)

  __shared__ bf16 smem2[3 * 12288];                   // 72 KB: [slot][A 4096 | B 8192]
  int tid = threadIdx.x, w = tid >> 6, lane = tid & 63;
  int wr = w >> 1, wc = w & 1;
  int fr = lane & 15, hi = lane >> 4;
  int qp = (hi ^ ((fr >> 1) & 3)) * 8;
  int srcq = ((lane & 3) ^ ((lane >> 3) & 3)) * 8;
  int srow = lane >> 2;

  f32x4 acc[4][8];
  #pragma unroll
  for (int m = 0; m < 4; m++)
    #pragma unroll
    for (int n = 0; n < 8; n++) acc[m][n] = (f32x4)0.f;

  const bf16* w2e = w2b + (long)e * D_DIM * HP;
  const bf16* aS[2];
  const bf16* bS[4];
  #pragma unroll
  for (int L = 0; L < 2; L++) {
    int ra = row_base + min(tm * 128 + w * 32 + L * 16 + srow, ne - 1);
    aS[L] = h + (long)ra * HP + k0 + srcq;
  }
  #pragma unroll
  for (int L = 0; L < 4; L++) {
    int rb = n0 + (L * 4 + w) * 16 + srow;
    bS[L] = w2e + (long)rb * HP + k0 + srcq;
  }

  bf16x8 af[4], bf0[4], bf1[4];

  G2_STAGE(0, 0); G2_STAGE(12288, 1);
  VMCNT(6); BAR();

  int sbC = 0, sbS = 24576;
  for (int t = 0; t < 42; t++) {                      // tiles 0..41; stage 2..43
    G2_READ0(sbC);
    G2_STAGE(sbS, t + 2);
    BAR();
    G2_MFMA0();
    G2_READ1(sbC);
    G2_MFMA1();
    LGKM0(); VMCNT(6); BAR();
    sbC += 12288; if (sbC > 24576) sbC = 0;
    sbS += 12288; if (sbS > 24576) sbS = 0;
  }
  { G2_READ0(sbC); BAR(); G2_MFMA0(); G2_READ1(sbC); G2_MFMA1(); LGKM0(); VMCNT(0); BAR();
    sbC += 12288; if (sbC > 24576) sbC = 0; }
  { G2_READ0(sbC); G2_MFMA0(); G2_READ1(sbC); G2_MFMA1(); }

  bf16* y = ks ? y1p : y0p;
  int crow4 = hi * 4;
  #pragma unroll
  for (int m = 0; m < 4; m++)
    #pragma unroll
    for (int j = 0; j < 4; j++) {
      int rloc = tm * 128 + wr * 64 + m * 16 + crow4 + j;
      if (rloc < ne) {
        long yrow = (long)(row_base + rloc) * D_DIM;
        #pragma unroll
        for (int n = 0; n < 8; n++) {
          int col2 = n0 + wc * 128 + n * 16 + fr;
          y[yrow + col2] = (bf16)acc[m][n][j];
        }
      }
    }
}

extern "C" void kernel_launch(void* const* d_in, const int* in_sizes, int n_in,
                              void* d_out, int out_size, void* d_ws, size_t ws_size,
                              hipStream_t stream) {
  const float* x  = (const float*)d_in[0];
  const float* gw = (const float*)d_in[1];
  const float* w1 = (const float*)d_in[2];
  const float* w3 = (const float*)d_in[3];
  const float* w2 = (const float*)d_in[4];
  float* out = (float*)d_out;

  char* ws = (char*)d_ws;
  int*   counts   = (int*)(ws);
  int*   cursor   = (int*)(ws + 64);
  int*   offs     = (int*)(ws + 128);
  int*   tlist    = (int*)(ws + 192);              // 544 B
  int*   tlist2   = (int*)(ws + 768);              // 288 B
  int*   topi     = (int*)(ws + 2048);
  float* topw     = (float*)(ws + 2048 + 65536);
  int*   rowoftok = (int*)(ws + 2048 + 131072);
  char*  big      = ws + 2048 + 327680;
  // Region plan: Bp [92.3 MB] holds (after gemm1): w2b [46.1] + y0 [33.5].
  // Xg [33.5] (dead after gemm1) holds y1. hbuf [92.3].
  bf16* Bp   = (bf16*)big;                                   // [8][5632][1024]
  bf16* w2b  = (bf16*)big;                                   // [8][1024][2816] (alias Bp)
  bf16* y0   = (bf16*)(big + 46137344);                      // [16384][1024] (alias Bp tail)
  bf16* Xg   = Bp + (size_t)E_NUM * NP * D_DIM;              // [16384][1024]
  bf16* y1   = Xg;                                           // alias (Xg dead after gemm1)
  bf16* hbuf = Xg + (size_t)NROWS * D_DIM;                   // [16384][2816]

  hipMemsetAsync((char*)d_out + (size_t)(out_size - 1) * sizeof(float), 0, sizeof(float), stream);
  hipMemsetAsync(ws, 0, 256, stream);   // counts, cursor

  int nbp = E_NUM * NP * 128;
  conv13_kernel<<<(nbp + 255) / 256, 256, 0, stream>>>(w1, w3, Bp);

  router_kernel<<<N_TOK / 4, 256, 0, stream>>>(x, gw, topi, topw, counts);
  tiles_kernel<<<1, 192, 0, stream>>>(counts, offs, tlist, tlist2);
  scatter_gather_kernel<<<NROWS / 64, 256, 0, stream>>>(topi, x, offs, cursor, rowoftok, Xg);

  gemm1_kernel<<<MAXT256 * 44, 256, 0, stream>>>(Xg, Bp, counts, offs, tlist2, hbuf);

  int w2n = E_NUM * D_DIM * (HP / 8);
  conv_w2_kernel<<<(w2n + 255) / 256, 256, 0, stream>>>(w2, w2b);

  gemm2_kernel<<<MAXTILES * 8, 256, 0, stream>>>(hbuf, w2b, counts, offs, tlist, y0, y1);
  combine_kernel<<<N_TOK / 4, 256, 0, stream>>>(y0, y1, rowoftok, topw, out);
}